// Round 5
// 2515.640 us; speedup vs baseline: 1.0816x; 1.0816x over previous
//
#include <hip/hip_runtime.h>
#include <stdint.h>

typedef unsigned short u16;
typedef uint32_t u32;
typedef __attribute__((ext_vector_type(8))) short short8;
typedef __attribute__((ext_vector_type(4))) float floatx4;

constexpr int BB = 128;     // batch
constexpr int TT = 64;      // time steps
constexpr int CC = 66;      // frame channels
constexpr int CPAD = 96;    // C padded to multiple of 32 (MFMA K-chunk)
constexpr int SS = 512;     // hidden
constexpr int NGATE = 1536; // 3*S
constexpr int NGRP = 8;     // independent batch groups (16 batches each)
constexpr int GBLK = 16;    // blocks per group (s-split by 32)
constexpr int GS = 16 * SS; // per-group state slab elements (16 x 512)

// State slabs (h0/h1/tstage) use FRAGMENT-ORDER layout:
//   slab[(s>>3)][m][s&7]  (dims [64][16][8], u16)
// so a consumer wave's MFMA A-fragment load `dwordx4` at
//   slab + kc*512 + lane*8
// is one fully CONTIGUOUS 1KB block per instruction (16 instrs = whole 16KB
// slab, contiguous).  Old layout ([m][s]) made each dwordx4 touch 64 distinct
// cache lines (1KB lane stride) -> ~1024 scattered MALL transactions per slab
// read; that storm dominated the 20us/step hop cost in round-0 profiling.

__device__ __forceinline__ u16 f2bf(float f) {
    u32 u = __float_as_uint(f);
    u32 r = (u + 0x7fffu + ((u >> 16) & 1u)) >> 16;
    return (u16)r;
}
__device__ __forceinline__ float bf2f(u16 h) {
    return __uint_as_float(((u32)h) << 16);
}
__device__ __forceinline__ float sigm(float x) { return 1.f / (1.f + __expf(-x)); }
__device__ __forceinline__ float tanh_f(float x) { return 1.f - 2.f / (1.f + __expf(2.f * x)); }

// ---- coherence-bypass primitives (MALL-coherent, no cache maintenance) ----
__device__ __forceinline__ void store_u16_cc(u16* p, u16 v) {
    asm volatile("global_store_short %0, %1, off sc0 sc1"
                 :: "v"(p), "v"((u32)v) : "memory");
}
__device__ __forceinline__ void load_issue_cc(const u16* p, short8& d) {
    asm volatile("global_load_dwordx4 %0, %1, off sc0 sc1"
                 : "=v"(d) : "v"(p));
}
__device__ __forceinline__ void vm_drain() {
    asm volatile("s_waitcnt vmcnt(0)" ::: "memory");
}

// ---------------------------------------------------------------------------
// prep1: bf16 conversion of x (padded to 96), the 4 GRU weight matrices,
// and Ws -> bf16 [80][512] (c-padded) for the MFMA frames epilogue.
// ---------------------------------------------------------------------------
__global__ void prep1_kernel(const float* __restrict__ x,
                             const float* __restrict__ Wih0,
                             const float* __restrict__ Whh0,
                             const float* __restrict__ Wih1,
                             const float* __restrict__ Whh1,
                             const float* __restrict__ Ws,
                             u16* __restrict__ xbf, u16* __restrict__ wi0,
                             u16* __restrict__ wh0, u16* __restrict__ wi1,
                             u16* __restrict__ wh1, u16* __restrict__ wsb)
{
    const int N_xbf = BB * TT * CPAD;
    const int N_wi0 = NGATE * CPAD;
    const int N_whh = NGATE * SS;
    const int N_wsb = 80 * SS;
    const long total = (long)N_xbf + N_wi0 + 3L * N_whh + N_wsb;
    for (long i = (long)blockIdx.x * blockDim.x + threadIdx.x; i < total;
         i += (long)gridDim.x * blockDim.x) {
        long idx = i;
        if (idx < N_xbf) {
            int c = idx % CPAD; int bt = idx / CPAD;
            float v = (c < CC) ? x[(long)bt * CC + c] : 0.f;
            xbf[idx] = f2bf(v); continue;
        }
        idx -= N_xbf;
        if (idx < N_wi0) {
            int c = idx % CPAD; int n = idx / CPAD;
            float v = (c < CC) ? Wih0[(long)n * CC + c] : 0.f;
            wi0[idx] = f2bf(v); continue;
        }
        idx -= N_wi0;
        if (idx < N_whh) { wh0[idx] = f2bf(Whh0[idx]); continue; }
        idx -= N_whh;
        if (idx < N_whh) { wi1[idx] = f2bf(Wih1[idx]); continue; }
        idx -= N_whh;
        if (idx < N_whh) { wh1[idx] = f2bf(Whh1[idx]); continue; }
        idx -= N_whh;
        {
            int s = idx % SS; int c = idx / SS;
            wsb[idx] = (c < CC) ? f2bf(Ws[(long)c * SS + s]) : (u16)0;
        }
    }
}

// ---------------------------------------------------------------------------
// prep2: M = Wih0[:, :66] @ Ws (bf16); c0vec = Wih0 @ bs; gi0i = x_last@Wih0^T
// ---------------------------------------------------------------------------
__global__ void prep2_kernel(const float* __restrict__ x,
                             const float* __restrict__ Wih0,
                             const float* __restrict__ Ws,
                             const float* __restrict__ bs,
                             u16* __restrict__ Mbf, float* __restrict__ c0vec,
                             float* __restrict__ gi0i)
{
    const long NM = (long)NGATE * SS;
    const long NC = NGATE;
    const long NG = (long)BB * NGATE;
    const long total = NM + NC + NG;
    for (long i = (long)blockIdx.x * blockDim.x + threadIdx.x; i < total;
         i += (long)gridDim.x * blockDim.x) {
        long idx = i;
        if (idx < NM) {
            int s = idx % SS; int g = idx / SS;
            float acc = 0.f;
            for (int c = 0; c < CC; ++c)
                acc += Wih0[(long)g * CC + c] * Ws[(long)c * SS + s];
            Mbf[idx] = f2bf(acc); continue;
        }
        idx -= NM;
        if (idx < NC) {
            int g = idx;
            float acc = 0.f;
            for (int c = 0; c < CC; ++c) acc += Wih0[(long)g * CC + c] * bs[c];
            c0vec[g] = acc; continue;
        }
        idx -= NC;
        {
            int g = idx % NGATE; int b = idx / NGATE;
            float acc = 0.f;
            const float* xl = x + ((long)b * TT + (TT - 1)) * CC;
            for (int c = 0; c < CC; ++c) acc += xl[c] * Wih0[(long)g * CC + c];
            gi0i[idx] = acc;
        }
    }
}

// ---------------------------------------------------------------------------
// A-fragment load from a fragment-order slab: 16 coherent dwordx4, each a
// CONTIGUOUS 1KB block (lane-consecutive addresses).  Fragment semantics
// identical to the old [m][s] load: lane(l15,quad) gets A[m=l15][k=kc*32+
// quad*8+j], verified:  kc*512 + lane*8 + j  ==  ((s>>3)*16+m)*8 + (s&7)
// with s = kc*32 + quad*8 + j, m = l15.
// ---------------------------------------------------------------------------
__device__ __forceinline__ void load_afrags(const u16* __restrict__ st,
                                            int lane, short8* a) {
#pragma unroll
    for (int kc = 0; kc < 16; ++kc)
        load_issue_cc(st + (long)kc * 512 + lane * 8, a[kc]);
}

#define MFMA_BF16(a, wp, acc) \
    acc = __builtin_amdgcn_mfma_f32_16x16x32_bf16(a, *(const short8*)(wp), acc, 0, 0, 0)

// Triple-gate MFMA over K=512 with register-resident A fragments.
__device__ __forceinline__ void mm3_reg(const short8* a,
                                        const u16* __restrict__ w0,
                                        const u16* __restrict__ w1,
                                        const u16* __restrict__ w2,
                                        floatx4& A0, floatx4& A1, floatx4& A2) {
#pragma unroll
    for (int kc = 0; kc < 16; ++kc) {
        const int k = kc << 5;
        MFMA_BF16(a[kc], w0 + k, A0);
        MFMA_BF16(a[kc], w1 + k, A1);
        MFMA_BF16(a[kc], w2 + k, A2);
    }
}

// Triple-gate MFMA, A direct from read-only cached global (x input, K=96).
template <int K>
__device__ __forceinline__ void mm3_g(const u16* __restrict__ aP,
                                      const u16* __restrict__ w0,
                                      const u16* __restrict__ w1,
                                      const u16* __restrict__ w2,
                                      floatx4& A0, floatx4& A1, floatx4& A2) {
#pragma unroll
    for (int k = 0; k < K; k += 32) {
        short8 a = *(const short8*)(aP + k);
        MFMA_BF16(a, w0 + k, A0);
        MFMA_BF16(a, w1 + k, A1);
        MFMA_BF16(a, w2 + k, A2);
    }
}

// ---------------------------------------------------------------------------
// Per-WAVE flag wait: layer-0 flags (32 ints) polled by lanes 0..31,
// layer-1 flags by lanes 32..63, single combined spin.  Relaxed agent-scope
// loads (MALL-coherent, proven).  No fences.
// ---------------------------------------------------------------------------
__device__ __forceinline__ void wait2(const int* __restrict__ f0, int t0,
                                      const int* __restrict__ f1, int t1) {
    const int lane = threadIdx.x & 63;
    const int* p = (lane < 32) ? (f0 + lane) : (f1 + (lane - 32));
    const int tgt = (lane < 32) ? t0 : t1;
    for (;;) {
        int v = __hip_atomic_load(p, __ATOMIC_RELAXED, __HIP_MEMORY_SCOPE_AGENT);
        if (__all(v >= tgt)) break;
        __builtin_amdgcn_s_sleep(1);
    }
    asm volatile("" ::: "memory");
}

__device__ __forceinline__ void set_flag(int* f, int v) {
    if ((threadIdx.x & 63) == 0)
        __hip_atomic_store(f, v, __ATOMIC_RELAXED, __HIP_MEMORY_SCOPE_AGENT);
}

// ---------------------------------------------------------------------------
// Persistent kernel, wave-decoupled dataflow.  Group g = blockIdx>>4 owns
// batches [16g,16g+16); block rank = blockIdx&15 owns s-slice 32*rank..+32.
// Waves 0,1 = layer-0 (s-sub 0/1), waves 2,3 = layer-1.  Each wave runs its
// own step loop gated only by per-wave completion flags; no __syncthreads,
// no LDS.  Buffers: h0 depth 4 (L0 runs ahead up to 3), h1/tstage depth 2.
// State slabs in fragment order (see top comment).
// ---------------------------------------------------------------------------
__global__ __launch_bounds__(256, 1) void persist_kernel(
    const u16* __restrict__ xbf,
    const u16* __restrict__ wi0, const u16* __restrict__ wh0,
    const u16* __restrict__ wi1, const u16* __restrict__ wh1,
    const u16* __restrict__ Mbf,
    const float* __restrict__ bih0, const float* __restrict__ bhh0,
    const float* __restrict__ bih1, const float* __restrict__ bhh1,
    const float* __restrict__ c0vec, const float* __restrict__ gi0i,
    const float* __restrict__ Wt, const float* __restrict__ bt,
    u16* __restrict__ h0buf,   // [NGRP][4][slab 8192]
    u16* __restrict__ h1buf,   // [NGRP][2][slab 8192]
    u16* __restrict__ tstage,  // [NGRP][2][slab 8192]
    u16* __restrict__ temps,   // [64][128][512] (cached; read by frames)
    int* __restrict__ gflags)  // [NGRP][64]: f0[32], f1[32]
{
    const int tid = threadIdx.x;
    const int wave = tid >> 6, lane = tid & 63;
    const int l15 = lane & 15, quad = lane >> 4;
    const int grp = blockIdx.x >> 4, rank = blockIdx.x & 15;
    const int b0g = grp * 16;
    const int wsub = wave & 1;
    const int sg = rank * 32 + wsub * 16 + l15;
    const bool l0w = wave < 2;

    // fragment-order store offset for this thread's s-column sg:
    //   elem offset = (sg>>3)*128 + (m)*8 + (sg&7),  m = quad*4 + r
    const int stoff = ((sg >> 3) << 7) + (sg & 7);

    u16* const h0g = h0buf + (long)grp * 4 * GS;
    u16* const h1g = h1buf + (long)grp * 2 * GS;
    u16* const tsg = tstage + (long)grp * 2 * GS;
    int* const f0 = gflags + grp * 64;
    int* const f1 = f0 + 32;
    const int myflag = rank * 2 + wsub;

    // ---- per-thread constants & register state ----
    float bir, biz, bin, bhn;
    float c0r = 0.f, c0z = 0.f, c0n = 0.f;
    float hf[4] = {0.f, 0.f, 0.f, 0.f};
    float gi[12];
    float wt[32]; float btv = 0.f;
    u32 wreg[4][16];
#pragma unroll
    for (int r = 0; r < 4; ++r)
#pragma unroll
        for (int i = 0; i < 16; ++i) wreg[r][i] = 0u;

    if (l0w) {
        bir = bih0[sg] + bhh0[sg];
        biz = bih0[512 + sg] + bhh0[512 + sg];
        bin = bih0[1024 + sg];
        bhn = bhh0[1024 + sg];
        c0r = c0vec[sg]; c0z = c0vec[512 + sg]; c0n = c0vec[1024 + sg];
#pragma unroll
        for (int g3 = 0; g3 < 3; ++g3)
#pragma unroll
            for (int r = 0; r < 4; ++r)
                gi[g3 * 4 + r] =
                    gi0i[(long)(b0g + quad * 4 + r) * NGATE + g3 * 512 + sg];
    } else {
        bir = bih1[sg] + bhh1[sg];
        biz = bih1[512 + sg] + bhh1[512 + sg];
        bin = bih1[1024 + sg];
        bhn = bhh1[1024 + sg];
#pragma unroll
        for (int j = 0; j < 32; ++j) wt[j] = Wt[j];
        btv = bt[0];
    }

    const u16 *wiR, *wiZ, *wiN, *whR, *whZ, *whN, *mR, *mZ, *mN;
    if (l0w) {
        wiR = wi0 + (long)sg * CPAD + quad * 8;
        wiZ = wi0 + (long)(512 + sg) * CPAD + quad * 8;
        wiN = wi0 + (long)(1024 + sg) * CPAD + quad * 8;
        whR = wh0 + (long)sg * SS + quad * 8;
        whZ = wh0 + (long)(512 + sg) * SS + quad * 8;
        whN = wh0 + (long)(1024 + sg) * SS + quad * 8;
        mR = Mbf + (long)sg * SS + quad * 8;
        mZ = Mbf + (long)(512 + sg) * SS + quad * 8;
        mN = Mbf + (long)(1024 + sg) * SS + quad * 8;
    } else {
        wiR = wi1 + (long)sg * SS + quad * 8;
        wiZ = wi1 + (long)(512 + sg) * SS + quad * 8;
        wiN = wi1 + (long)(1024 + sg) * SS + quad * 8;
        whR = wh1 + (long)sg * SS + quad * 8;
        whZ = wh1 + (long)(512 + sg) * SS + quad * 8;
        whN = wh1 + (long)(1024 + sg) * SS + quad * 8;
        mR = mZ = mN = nullptr;
    }

    short8 fa[16], fb[16];

    if (l0w) {
        // ================= layer-0 wave: 127 steps =================
        // encoder t = 0..62: consume h0(t), x[t]; produce h0(t+1)
        for (int t = 0; t < 63; ++t) {
            wait2(f0, t, f1, t - 3);   // data ready + depth-4 overwrite guard
            load_afrags(h0g + (long)(t & 3) * GS, lane, fa);
            floatx4 aR = {0,0,0,0}, aZ = aR, aNI = aR, aNH = aR;
            const u16* aP = xbf + ((long)(b0g + l15) * TT + t) * CPAD + quad * 8;
            mm3_g<CPAD>(aP, wiR, wiZ, wiN, aR, aZ, aNI);
            vm_drain();
            mm3_reg(fa, whR, whZ, whN, aR, aZ, aNH);
            u16* dst = h0g + (long)((t + 1) & 3) * GS + stoff;
#pragma unroll
            for (int r = 0; r < 4; ++r) {
                float rr = sigm(aR[r] + bir);
                float zz = sigm(aZ[r] + biz);
                float nn = tanh_f(aNI[r] + bin + rr * (aNH[r] + bhn));
                float hv = (1.f - zz) * nn + zz * hf[r];
                hf[r] = hv;
                store_u16_cc(dst + (quad * 4 + r) * 8, f2bf(hv));
            }
            vm_drain();
            set_flag(f0 + myflag, t + 1);
        }
        // decoder d = 0..63: step index t = 63+d; produce h0 state 64+d
        for (int d = 0; d < 64; ++d) {
            const int t = 63 + d;
            wait2(f0, t, f1, (d > 0) ? t : 60);
            if (d > 0) {
                load_afrags(tsg + (long)((d - 1) & 1) * GS, lane, fb);
            }
            load_afrags(h0g + (long)(t & 3) * GS, lane, fa);
            vm_drain();
            if (d > 0) {   // gi(d) = gi(d-1) + M @ temp(d-1) + c0
                floatx4 tR = {0,0,0,0}, tZ = tR, tN = tR;
                mm3_reg(fb, mR, mZ, mN, tR, tZ, tN);
#pragma unroll
                for (int r = 0; r < 4; ++r) {
                    gi[r] += tR[r] + c0r;
                    gi[4 + r] += tZ[r] + c0z;
                    gi[8 + r] += tN[r] + c0n;
                }
            }
            floatx4 hR = {0,0,0,0}, hZ = hR, hN4 = hR;
            mm3_reg(fa, whR, whZ, whN, hR, hZ, hN4);
            u16* dst = h0g + (long)((t + 1) & 3) * GS + stoff;
#pragma unroll
            for (int r = 0; r < 4; ++r) {
                float rr = sigm(gi[r] + hR[r] + bir);
                float zz = sigm(gi[4 + r] + hZ[r] + biz);
                float nn = tanh_f(gi[8 + r] + bin + rr * (hN4[r] + bhn));
                float hv = (1.f - zz) * nn + zz * hf[r];
                hf[r] = hv;
                store_u16_cc(dst + (quad * 4 + r) * 8, f2bf(hv));
            }
            vm_drain();
            set_flag(f0 + myflag, t + 1);
        }
    } else {
        // ================= layer-1 wave: 127 steps =================
        // encoder u = 0..62: consume h0(u+1), h1(u); produce h1(u+1) + window
        for (int u = 0; u < 63; ++u) {
            wait2(f0, u + 1, f1, u);
            load_afrags(h0g + (long)((u + 1) & 3) * GS, lane, fa);
            load_afrags(h1g + (long)(u & 1) * GS, lane, fb);
            vm_drain();
            floatx4 aR = {0,0,0,0}, aZ = aR, aNI = aR, aNH = aR;
            mm3_reg(fa, wiR, wiZ, wiN, aR, aZ, aNI);
            mm3_reg(fb, whR, whZ, whN, aR, aZ, aNH);
            u16* dst = h1g + (long)((u + 1) & 1) * GS + stoff;
#pragma unroll
            for (int r = 0; r < 4; ++r) {
                float rr = sigm(aR[r] + bir);
                float zz = sigm(aZ[r] + biz);
                float nn = tanh_f(aNI[r] + bin + rr * (aNH[r] + bhn));
                float hv = (1.f - zz) * nn + zz * hf[r];
                hf[r] = hv;
                u16 hb = f2bf(hv);
                store_u16_cc(dst + (quad * 4 + r) * 8, hb);
#pragma unroll
                for (int i = 0; i < 15; ++i)
                    wreg[r][i] = (wreg[r][i] >> 16) | (wreg[r][i + 1] << 16);
                wreg[r][15] = (wreg[r][15] >> 16) | ((u32)hb << 16);
            }
            vm_drain();
            set_flag(f1 + myflag, u + 1);
        }
        // decoder d = 0..63: step u = 63+d; produce h1(64+d), temp(d)
        for (int d = 0; d < 64; ++d) {
            const int u = 63 + d;
            wait2(f0, u + 1, f1, u);
            load_afrags(h0g + (long)((u + 1) & 3) * GS, lane, fa);
            load_afrags(h1g + (long)(u & 1) * GS, lane, fb);
            vm_drain();
            floatx4 aR = {0,0,0,0}, aZ = aR, aNI = aR, aNH = aR;
            mm3_reg(fa, wiR, wiZ, wiN, aR, aZ, aNI);
            mm3_reg(fb, whR, whZ, whN, aR, aZ, aNH);
            u16* dst = h1g + (long)((u + 1) & 1) * GS + stoff;
            u16* tdst = tsg + (long)(d & 1) * GS + stoff;
            u16* tOut = temps + (long)d * (BB * SS);
#pragma unroll
            for (int r = 0; r < 4; ++r) {
                float rr = sigm(aR[r] + bir);
                float zz = sigm(aZ[r] + biz);
                float nn = tanh_f(aNI[r] + bin + rr * (aNH[r] + bhn));
                float hv = (1.f - zz) * nn + zz * hf[r];
                hf[r] = hv;
                u16 hb = f2bf(hv);
                store_u16_cc(dst + (quad * 4 + r) * 8, hb);
#pragma unroll
                for (int i = 0; i < 15; ++i)
                    wreg[r][i] = (wreg[r][i] >> 16) | (wreg[r][i + 1] << 16);
                wreg[r][15] = (wreg[r][15] >> 16) | ((u32)hb << 16);
                float tacc = btv;
#pragma unroll
                for (int i = 0; i < 16; ++i) {
                    u32 wv = wreg[r][i];
                    tacc += __uint_as_float(wv << 16) * wt[2 * i];
                    tacc += __uint_as_float(wv & 0xffff0000u) * wt[2 * i + 1];
                }
                u16 tb = f2bf(tacc);
                store_u16_cc(tdst + (quad * 4 + r) * 8, tb);
                tOut[(long)(b0g + quad * 4 + r) * SS + sg] = tb;  // cached, old layout
            }
            vm_drain();
            set_flag(f1 + myflag, u + 1);
        }
    }
}

// ---------------------------------------------------------------------------
// frames epilogue (parallel, MFMA): per batch b,
//   P[e][c] = temp(e)[b] . Ws[c];  frames[b][e][c] = x_last + cumsum(P + bs)
// Wave w computes e-tile w (16 e-rows) x 5 c-tiles via 16x16x32 MFMA.
// ---------------------------------------------------------------------------
__global__ __launch_bounds__(256) void frames_kernel(
    const u16* __restrict__ temps, const float* __restrict__ x,
    const u16* __restrict__ wsb, const float* __restrict__ bs,
    float* __restrict__ outp)
{
    const int b = blockIdx.x, tid = threadIdx.x;
    const int wave = tid >> 6, lane = tid & 63;
    const int l15 = lane & 15, quad = lane >> 4;
    __shared__ float P[64][81];

    const int e0 = wave * 16;
    floatx4 acc[5];
#pragma unroll
    for (int ct = 0; ct < 5; ++ct) acc[ct] = (floatx4){0.f, 0.f, 0.f, 0.f};
    const u16* aBase =
        temps + (long)(e0 + l15) * (BB * SS) + (long)b * SS + quad * 8;
#pragma unroll
    for (int kc = 0; kc < 16; ++kc) {
        short8 a = *(const short8*)(aBase + kc * 32);
#pragma unroll
        for (int ct = 0; ct < 5; ++ct) {
            const u16* wp = wsb + (long)(ct * 16 + l15) * SS + quad * 8 + kc * 32;
            MFMA_BF16(a, wp, acc[ct]);
        }
    }
#pragma unroll
    for (int ct = 0; ct < 5; ++ct)
#pragma unroll
        for (int r = 0; r < 4; ++r)
            P[e0 + quad * 4 + r][ct * 16 + l15] = acc[ct][r];
    __syncthreads();

    const int c = tid;
    if (c < CC) {
        float cum = x[((long)b * TT + (TT - 1)) * CC + c];
        const float bsv = bs[c];
        for (int e = 0; e < TT; ++e) {
            cum += P[e][c] + bsv;
            outp[(long)b * TT * CC + (long)e * CC + c] = cum;
        }
    }
}

// ---------------------------------------------------------------------------
extern "C" void kernel_launch(void* const* d_in, const int* in_sizes, int n_in,
                              void* d_out, int out_size, void* d_ws, size_t ws_size,
                              hipStream_t stream)
{
    const float* x    = (const float*)d_in[0];
    const float* Wih0 = (const float*)d_in[1];
    const float* Whh0 = (const float*)d_in[2];
    const float* bih0 = (const float*)d_in[3];
    const float* bhh0 = (const float*)d_in[4];
    const float* Wih1 = (const float*)d_in[5];
    const float* Whh1 = (const float*)d_in[6];
    const float* bih1 = (const float*)d_in[7];
    const float* bhh1 = (const float*)d_in[8];
    const float* Wt   = (const float*)d_in[9];
    const float* bt   = (const float*)d_in[10];
    const float* Ws   = (const float*)d_in[11];
    const float* bs   = (const float*)d_in[12];
    float* outp = (float*)d_out;

    char* p = (char*)d_ws;
    auto alloc = [&](size_t bytes) -> char* {
        char* r = p; p += (bytes + 255) & ~(size_t)255; return r;
    };
    u16* h0buf = (u16*)alloc((size_t)NGRP * 4 * GS * 2);
    u16* h1buf = (u16*)alloc((size_t)NGRP * 2 * GS * 2);
    u16* tstage = (u16*)alloc((size_t)NGRP * 2 * GS * 2);
    u16* xbf = (u16*)alloc((size_t)BB * TT * CPAD * 2);
    u16* wi0 = (u16*)alloc((size_t)NGATE * CPAD * 2);
    u16* wh0 = (u16*)alloc((size_t)NGATE * SS * 2);
    u16* wi1 = (u16*)alloc((size_t)NGATE * SS * 2);
    u16* wh1 = (u16*)alloc((size_t)NGATE * SS * 2);
    u16* Mbf = (u16*)alloc((size_t)NGATE * SS * 2);
    u16* wsb = (u16*)alloc((size_t)80 * SS * 2);
    float* c0vec = (float*)alloc((size_t)NGATE * 4);
    float* gi0i  = (float*)alloc((size_t)BB * NGATE * 4);
    u16* temps = (u16*)alloc((size_t)TT * BB * SS * 2);
    int* gflags = (int*)alloc((size_t)NGRP * 64 * 4);

    hipMemsetAsync(h0buf, 0, (size_t)NGRP * 4 * GS * 2, stream);
    hipMemsetAsync(h1buf, 0, (size_t)NGRP * 2 * GS * 2, stream);
    hipMemsetAsync(gflags, 0, (size_t)NGRP * 64 * 4, stream);

    prep1_kernel<<<1024, 256, 0, stream>>>(x, Wih0, Whh0, Wih1, Whh1, Ws,
                                           xbf, wi0, wh0, wi1, wh1, wsb);
    prep2_kernel<<<1024, 256, 0, stream>>>(x, Wih0, Ws, bs, Mbf, c0vec, gi0i);

    persist_kernel<<<NGRP * GBLK, 256, 0, stream>>>(
        xbf, wi0, wh0, wi1, wh1, Mbf, bih0, bhh0, bih1, bhh1,
        c0vec, gi0i, Wt, bt, h0buf, h1buf, tstage, temps, gflags);

    frames_kernel<<<BB, 256, 0, stream>>>(temps, x, wsb, bs, outp);
}

// Round 6
// 2479.785 us; speedup vs baseline: 1.0973x; 1.0145x over previous
//
#include <hip/hip_runtime.h>
#include <stdint.h>

typedef unsigned short u16;
typedef uint32_t u32;
typedef __attribute__((ext_vector_type(8))) short short8;
typedef __attribute__((ext_vector_type(4))) float floatx4;
typedef __attribute__((ext_vector_type(2))) unsigned int u32x2;

constexpr int BB = 128;     // batch
constexpr int TT = 64;      // time steps
constexpr int CC = 66;      // frame channels
constexpr int CPAD = 96;    // C padded to multiple of 32 (MFMA K-chunk)
constexpr int SS = 512;     // hidden
constexpr int NGATE = 1536; // 3*S
constexpr int NGRP = 8;     // independent batch groups (16 batches each)
constexpr int GBLK = 16;    // blocks per group (s-split by 32)
constexpr int GS = 16 * SS; // per-group state slab elements (16 x 512)

// State slabs (h0/h1/tstage) use FRAGMENT-ORDER layout:
//   slab[(s>>3)][m][s&7]  (dims [64][16][8], u16)
// Consumer reads: dwordx4 at slab + kc*512 + lane*8 -> contiguous 1KB/instr.
// Producer writes (this round): wave stages its 512B contribution in LDS,
// then 64 lanes emit one dwordx2 each -> 64 full-line coalesced stores
// (was: 256 scalar 2B system-scope stores -> MALL partial-line RMW storm;
// visible as WRITE_SIZE 51->92MB regression in round-5 counters).

__device__ __forceinline__ u16 f2bf(float f) {
    u32 u = __float_as_uint(f);
    u32 r = (u + 0x7fffu + ((u >> 16) & 1u)) >> 16;
    return (u16)r;
}
__device__ __forceinline__ float bf2f(u16 h) {
    return __uint_as_float(((u32)h) << 16);
}
__device__ __forceinline__ float sigm(float x) { return 1.f / (1.f + __expf(-x)); }
__device__ __forceinline__ float tanh_f(float x) { return 1.f - 2.f / (1.f + __expf(2.f * x)); }

// ---- coherence-bypass primitives (MALL-coherent, no cache maintenance) ----
__device__ __forceinline__ void load_issue_cc(const u16* p, short8& d) {
    asm volatile("global_load_dwordx4 %0, %1, off sc0 sc1"
                 : "=v"(d) : "v"(p));
}
__device__ __forceinline__ void store_u64_cc(u16* p, u32x2 v) {
    asm volatile("global_store_dwordx2 %0, %1, off sc0 sc1"
                 :: "v"(p), "v"(v) : "memory");
}
__device__ __forceinline__ void vm_drain() {
    asm volatile("s_waitcnt vmcnt(0)" ::: "memory");
}

// ---------------------------------------------------------------------------
// prep1: bf16 conversion of x (padded to 96), the 4 GRU weight matrices,
// and Ws -> bf16 [80][512] (c-padded) for the MFMA frames epilogue.
// ---------------------------------------------------------------------------
__global__ void prep1_kernel(const float* __restrict__ x,
                             const float* __restrict__ Wih0,
                             const float* __restrict__ Whh0,
                             const float* __restrict__ Wih1,
                             const float* __restrict__ Whh1,
                             const float* __restrict__ Ws,
                             u16* __restrict__ xbf, u16* __restrict__ wi0,
                             u16* __restrict__ wh0, u16* __restrict__ wi1,
                             u16* __restrict__ wh1, u16* __restrict__ wsb)
{
    const int N_xbf = BB * TT * CPAD;
    const int N_wi0 = NGATE * CPAD;
    const int N_whh = NGATE * SS;
    const int N_wsb = 80 * SS;
    const long total = (long)N_xbf + N_wi0 + 3L * N_whh + N_wsb;
    for (long i = (long)blockIdx.x * blockDim.x + threadIdx.x; i < total;
         i += (long)gridDim.x * blockDim.x) {
        long idx = i;
        if (idx < N_xbf) {
            int c = idx % CPAD; int bt = idx / CPAD;
            float v = (c < CC) ? x[(long)bt * CC + c] : 0.f;
            xbf[idx] = f2bf(v); continue;
        }
        idx -= N_xbf;
        if (idx < N_wi0) {
            int c = idx % CPAD; int n = idx / CPAD;
            float v = (c < CC) ? Wih0[(long)n * CC + c] : 0.f;
            wi0[idx] = f2bf(v); continue;
        }
        idx -= N_wi0;
        if (idx < N_whh) { wh0[idx] = f2bf(Whh0[idx]); continue; }
        idx -= N_whh;
        if (idx < N_whh) { wi1[idx] = f2bf(Wih1[idx]); continue; }
        idx -= N_whh;
        if (idx < N_whh) { wh1[idx] = f2bf(Whh1[idx]); continue; }
        idx -= N_whh;
        {
            int s = idx % SS; int c = idx / SS;
            wsb[idx] = (c < CC) ? f2bf(Ws[(long)c * SS + s]) : (u16)0;
        }
    }
}

// ---------------------------------------------------------------------------
// prep2: M = Wih0[:, :66] @ Ws (bf16); c0vec = Wih0 @ bs; gi0i = x_last@Wih0^T
// ---------------------------------------------------------------------------
__global__ void prep2_kernel(const float* __restrict__ x,
                             const float* __restrict__ Wih0,
                             const float* __restrict__ Ws,
                             const float* __restrict__ bs,
                             u16* __restrict__ Mbf, float* __restrict__ c0vec,
                             float* __restrict__ gi0i)
{
    const long NM = (long)NGATE * SS;
    const long NC = NGATE;
    const long NG = (long)BB * NGATE;
    const long total = NM + NC + NG;
    for (long i = (long)blockIdx.x * blockDim.x + threadIdx.x; i < total;
         i += (long)gridDim.x * blockDim.x) {
        long idx = i;
        if (idx < NM) {
            int s = idx % SS; int g = idx / SS;
            float acc = 0.f;
            for (int c = 0; c < CC; ++c)
                acc += Wih0[(long)g * CC + c] * Ws[(long)c * SS + s];
            Mbf[idx] = f2bf(acc); continue;
        }
        idx -= NM;
        if (idx < NC) {
            int g = idx;
            float acc = 0.f;
            for (int c = 0; c < CC; ++c) acc += Wih0[(long)g * CC + c] * bs[c];
            c0vec[g] = acc; continue;
        }
        idx -= NC;
        {
            int g = idx % NGATE; int b = idx / NGATE;
            float acc = 0.f;
            const float* xl = x + ((long)b * TT + (TT - 1)) * CC;
            for (int c = 0; c < CC; ++c) acc += xl[c] * Wih0[(long)g * CC + c];
            gi0i[idx] = acc;
        }
    }
}

// ---------------------------------------------------------------------------
// A-fragment load from a fragment-order slab: 16 coherent dwordx4, each a
// CONTIGUOUS 1KB block.  lane(l15,quad) gets A[m=l15][k=kc*32+quad*8+j].
// ---------------------------------------------------------------------------
__device__ __forceinline__ void load_afrags(const u16* __restrict__ st,
                                            int lane, short8* a) {
#pragma unroll
    for (int kc = 0; kc < 16; ++kc)
        load_issue_cc(st + (long)kc * 512 + lane * 8, a[kc]);
}

#define MFMA_BF16(a, wp, acc) \
    acc = __builtin_amdgcn_mfma_f32_16x16x32_bf16(a, *(const short8*)(wp), acc, 0, 0, 0)

// Triple-gate MFMA over K=512 with register-resident A fragments.
__device__ __forceinline__ void mm3_reg(const short8* a,
                                        const u16* __restrict__ w0,
                                        const u16* __restrict__ w1,
                                        const u16* __restrict__ w2,
                                        floatx4& A0, floatx4& A1, floatx4& A2) {
#pragma unroll
    for (int kc = 0; kc < 16; ++kc) {
        const int k = kc << 5;
        MFMA_BF16(a[kc], w0 + k, A0);
        MFMA_BF16(a[kc], w1 + k, A1);
        MFMA_BF16(a[kc], w2 + k, A2);
    }
}

// Triple-gate MFMA, A direct from read-only cached global (x input, K=96).
template <int K>
__device__ __forceinline__ void mm3_g(const u16* __restrict__ aP,
                                      const u16* __restrict__ w0,
                                      const u16* __restrict__ w1,
                                      const u16* __restrict__ w2,
                                      floatx4& A0, floatx4& A1, floatx4& A2) {
#pragma unroll
    for (int k = 0; k < K; k += 32) {
        short8 a = *(const short8*)(aP + k);
        MFMA_BF16(a, w0 + k, A0);
        MFMA_BF16(a, w1 + k, A1);
        MFMA_BF16(a, w2 + k, A2);
    }
}

// ---------------------------------------------------------------------------
// Flag waits (relaxed agent-scope loads, MALL-coherent; proven rounds 0/5).
// wait2: lanes 0..31 poll f0[], lanes 32..63 poll f1[].
// wait1: all lanes poll f[lane&31] (single array).
// ---------------------------------------------------------------------------
__device__ __forceinline__ void wait2(const int* __restrict__ f0, int t0,
                                      const int* __restrict__ f1, int t1) {
    const int lane = threadIdx.x & 63;
    const int* p = (lane < 32) ? (f0 + lane) : (f1 + (lane - 32));
    const int tgt = (lane < 32) ? t0 : t1;
    for (;;) {
        int v = __hip_atomic_load(p, __ATOMIC_RELAXED, __HIP_MEMORY_SCOPE_AGENT);
        if (__all(v >= tgt)) break;
        __builtin_amdgcn_s_sleep(1);
    }
    asm volatile("" ::: "memory");
}

__device__ __forceinline__ void wait1(const int* __restrict__ f, int tgt) {
    const int lane = threadIdx.x & 63;
    const int* p = f + (lane & 31);
    for (;;) {
        int v = __hip_atomic_load(p, __ATOMIC_RELAXED, __HIP_MEMORY_SCOPE_AGENT);
        if (__all(v >= tgt)) break;
        __builtin_amdgcn_s_sleep(1);
    }
    asm volatile("" ::: "memory");
}

__device__ __forceinline__ void set_flag(int* f, int v) {
    if ((threadIdx.x & 63) == 0)
        __hip_atomic_store(f, v, __ATOMIC_RELAXED, __HIP_MEMORY_SCOPE_AGENT);
}

// ---------------------------------------------------------------------------
// staged_store: wave-local LDS transpose -> 64 coalesced dwordx2 stores.
// Wave's 256 u16 (16 sg x 16 m) cover elems [wbase, wbase+256) of the slab.
// LDS local idx for (r, lane): (l15>>3)*128 + (quad*4+r)*8 + (l15&7)
// equals global_off - wbase (verified: sg = S0 + l15, S0 multiple of 16).
// Intra-wave DS ordering is in-order; wave_barrier pins compiler order.
// ---------------------------------------------------------------------------
__device__ __forceinline__ void staged_store(u16* __restrict__ gdst,  // slab+wbase
                                             u16* __restrict__ lds,   // 256 elems
                                             const u16 hb[4],
                                             int l15, int quad, int lane)
{
#pragma unroll
    for (int r = 0; r < 4; ++r)
        lds[((l15 >> 3) << 7) + ((quad << 2) + r) * 8 + (l15 & 7)] = hb[r];
    __builtin_amdgcn_wave_barrier();
    const u32* lp = (const u32*)(lds + (lane << 2));
    u32x2 v; v[0] = lp[0]; v[1] = lp[1];
    store_u64_cc(gdst + (lane << 2), v);
    __builtin_amdgcn_wave_barrier();
}

// ---------------------------------------------------------------------------
// Persistent kernel, wave-decoupled dataflow.  Group g = blockIdx>>4 owns
// batches [16g,16g+16); block rank = blockIdx&15 owns s-slice 32*rank..+32.
// Waves 0,1 = layer-0 (s-sub 0/1), waves 2,3 = layer-1.  Per-wave flag gating;
// no __syncthreads.  h0 depth 4 (L0 runs ahead up to 3), h1/tstage depth 2.
// Round-6: split waits (compute off critical path) + coalesced staged stores.
// ---------------------------------------------------------------------------
__global__ __launch_bounds__(256, 1) void persist_kernel(
    const u16* __restrict__ xbf,
    const u16* __restrict__ wi0, const u16* __restrict__ wh0,
    const u16* __restrict__ wi1, const u16* __restrict__ wh1,
    const u16* __restrict__ Mbf,
    const float* __restrict__ bih0, const float* __restrict__ bhh0,
    const float* __restrict__ bih1, const float* __restrict__ bhh1,
    const float* __restrict__ c0vec, const float* __restrict__ gi0i,
    const float* __restrict__ Wt, const float* __restrict__ bt,
    u16* __restrict__ h0buf,   // [NGRP][4][slab 8192]
    u16* __restrict__ h1buf,   // [NGRP][2][slab 8192]
    u16* __restrict__ tstage,  // [NGRP][2][slab 8192]
    u16* __restrict__ temps,   // [64][128][512] (cached; read by frames)
    int* __restrict__ gflags)  // [NGRP][64]: f0[32], f1[32]
{
    const int tid = threadIdx.x;
    const int wave = tid >> 6, lane = tid & 63;
    const int l15 = lane & 15, quad = lane >> 4;
    const int grp = blockIdx.x >> 4, rank = blockIdx.x & 15;
    const int b0g = grp * 16;
    const int wsub = wave & 1;
    const int sg = rank * 32 + wsub * 16 + l15;
    const bool l0w = wave < 2;

    __shared__ u16 stg[4][512];           // per-wave: [0..255] h, [256..511] t
    u16* const ldsH = &stg[wave][0];
    u16* const ldsT = &stg[wave][256];

    // wave's slab element base: (S0>>3)*128, S0 = rank*32 + wsub*16
    const int wbase = (rank * 4 + wsub * 2) << 7;

    u16* const h0g = h0buf + (long)grp * 4 * GS;
    u16* const h1g = h1buf + (long)grp * 2 * GS;
    u16* const tsg = tstage + (long)grp * 2 * GS;
    int* const f0 = gflags + grp * 64;
    int* const f1 = f0 + 32;
    const int myflag = rank * 2 + wsub;

    // ---- per-thread constants & register state ----
    float bir, biz, bin, bhn;
    float c0r = 0.f, c0z = 0.f, c0n = 0.f;
    float hf[4] = {0.f, 0.f, 0.f, 0.f};
    float gi[12];
    float wt[32]; float btv = 0.f;
    u32 wreg[4][16];
#pragma unroll
    for (int r = 0; r < 4; ++r)
#pragma unroll
        for (int i = 0; i < 16; ++i) wreg[r][i] = 0u;

    if (l0w) {
        bir = bih0[sg] + bhh0[sg];
        biz = bih0[512 + sg] + bhh0[512 + sg];
        bin = bih0[1024 + sg];
        bhn = bhh0[1024 + sg];
        c0r = c0vec[sg]; c0z = c0vec[512 + sg]; c0n = c0vec[1024 + sg];
#pragma unroll
        for (int g3 = 0; g3 < 3; ++g3)
#pragma unroll
            for (int r = 0; r < 4; ++r)
                gi[g3 * 4 + r] =
                    gi0i[(long)(b0g + quad * 4 + r) * NGATE + g3 * 512 + sg];
    } else {
        bir = bih1[sg] + bhh1[sg];
        biz = bih1[512 + sg] + bhh1[512 + sg];
        bin = bih1[1024 + sg];
        bhn = bhh1[1024 + sg];
#pragma unroll
        for (int j = 0; j < 32; ++j) wt[j] = Wt[j];
        btv = bt[0];
    }

    const u16 *wiR, *wiZ, *wiN, *whR, *whZ, *whN, *mR, *mZ, *mN;
    if (l0w) {
        wiR = wi0 + (long)sg * CPAD + quad * 8;
        wiZ = wi0 + (long)(512 + sg) * CPAD + quad * 8;
        wiN = wi0 + (long)(1024 + sg) * CPAD + quad * 8;
        whR = wh0 + (long)sg * SS + quad * 8;
        whZ = wh0 + (long)(512 + sg) * SS + quad * 8;
        whN = wh0 + (long)(1024 + sg) * SS + quad * 8;
        mR = Mbf + (long)sg * SS + quad * 8;
        mZ = Mbf + (long)(512 + sg) * SS + quad * 8;
        mN = Mbf + (long)(1024 + sg) * SS + quad * 8;
    } else {
        wiR = wi1 + (long)sg * SS + quad * 8;
        wiZ = wi1 + (long)(512 + sg) * SS + quad * 8;
        wiN = wi1 + (long)(1024 + sg) * SS + quad * 8;
        whR = wh1 + (long)sg * SS + quad * 8;
        whZ = wh1 + (long)(512 + sg) * SS + quad * 8;
        whN = wh1 + (long)(1024 + sg) * SS + quad * 8;
        mR = mZ = mN = nullptr;
    }

    short8 fa[16], fb[16];

    if (l0w) {
        // ================= layer-0 wave: 127 steps =================
        // encoder t = 0..62: consume h0(t), x[t]; produce h0(t+1)
        for (int t = 0; t < 63; ++t) {
            wait2(f0, t, f1, t - 3);   // data ready + depth-4 overwrite guard
            load_afrags(h0g + (long)(t & 3) * GS, lane, fa);
            floatx4 aR = {0,0,0,0}, aZ = aR, aNI = aR, aNH = aR;
            const u16* aP = xbf + ((long)(b0g + l15) * TT + t) * CPAD + quad * 8;
            mm3_g<CPAD>(aP, wiR, wiZ, wiN, aR, aZ, aNI);
            vm_drain();
            mm3_reg(fa, whR, whZ, whN, aR, aZ, aNH);
            u16 hb[4];
#pragma unroll
            for (int r = 0; r < 4; ++r) {
                float rr = sigm(aR[r] + bir);
                float zz = sigm(aZ[r] + biz);
                float nn = tanh_f(aNI[r] + bin + rr * (aNH[r] + bhn));
                float hv = (1.f - zz) * nn + zz * hf[r];
                hf[r] = hv;
                hb[r] = f2bf(hv);
            }
            staged_store(h0g + (long)((t + 1) & 3) * GS + wbase, ldsH, hb,
                         l15, quad, lane);
            vm_drain();
            set_flag(f0 + myflag, t + 1);
        }
        // decoder d = 0..63: step index t = 63+d; produce h0 state 64+d
        for (int d = 0; d < 64; ++d) {
            const int t = 63 + d;
            wait2(f0, t, f1, t - 3);   // h0 ready + depth-4 overwrite guard
            load_afrags(h0g + (long)(t & 3) * GS, lane, fa);
            vm_drain();
            floatx4 hR = {0,0,0,0}, hZ = hR, hN4 = hR;
            mm3_reg(fa, whR, whZ, whN, hR, hZ, hN4);   // off critical path
            if (d > 0) {   // gi(d) = gi(d-1) + M @ temp(d-1) + c0
                wait1(f1, t);                            // temp(d-1) ready
                load_afrags(tsg + (long)((d - 1) & 1) * GS, lane, fb);
                vm_drain();
                floatx4 tR = {0,0,0,0}, tZ = tR, tN = tR;
                mm3_reg(fb, mR, mZ, mN, tR, tZ, tN);
#pragma unroll
                for (int r = 0; r < 4; ++r) {
                    gi[r] += tR[r] + c0r;
                    gi[4 + r] += tZ[r] + c0z;
                    gi[8 + r] += tN[r] + c0n;
                }
            }
            u16 hb[4];
#pragma unroll
            for (int r = 0; r < 4; ++r) {
                float rr = sigm(gi[r] + hR[r] + bir);
                float zz = sigm(gi[4 + r] + hZ[r] + biz);
                float nn = tanh_f(gi[8 + r] + bin + rr * (hN4[r] + bhn));
                float hv = (1.f - zz) * nn + zz * hf[r];
                hf[r] = hv;
                hb[r] = f2bf(hv);
            }
            staged_store(h0g + (long)((t + 1) & 3) * GS + wbase, ldsH, hb,
                         l15, quad, lane);
            vm_drain();
            set_flag(f0 + myflag, t + 1);
        }
    } else {
        // ================= layer-1 wave: 127 steps =================
        // encoder u = 0..62: consume h0(u+1), h1(u); produce h1(u+1) + window
        for (int u = 0; u < 63; ++u) {
            wait1(f1, u);              // h1(u) ready (also h1 overwrite guard)
            load_afrags(h1g + (long)(u & 1) * GS, lane, fb);
            vm_drain();
            floatx4 aR = {0,0,0,0}, aZ = aR, aNI = aR, aNH = aR;
            mm3_reg(fb, whR, whZ, whN, aR, aZ, aNH);   // off critical path
            wait1(f0, u + 1);          // fresh h0(u+1)
            load_afrags(h0g + (long)((u + 1) & 3) * GS, lane, fa);
            vm_drain();
            mm3_reg(fa, wiR, wiZ, wiN, aR, aZ, aNI);
            u16 hb[4];
#pragma unroll
            for (int r = 0; r < 4; ++r) {
                float rr = sigm(aR[r] + bir);
                float zz = sigm(aZ[r] + biz);
                float nn = tanh_f(aNI[r] + bin + rr * (aNH[r] + bhn));
                float hv = (1.f - zz) * nn + zz * hf[r];
                hf[r] = hv;
                u16 v = f2bf(hv);
                hb[r] = v;
#pragma unroll
                for (int i = 0; i < 15; ++i)
                    wreg[r][i] = (wreg[r][i] >> 16) | (wreg[r][i + 1] << 16);
                wreg[r][15] = (wreg[r][15] >> 16) | ((u32)v << 16);
            }
            staged_store(h1g + (long)((u + 1) & 1) * GS + wbase, ldsH, hb,
                         l15, quad, lane);
            vm_drain();
            set_flag(f1 + myflag, u + 1);
        }
        // decoder d = 0..63: step u = 63+d; produce h1(64+d), temp(d)
        for (int d = 0; d < 64; ++d) {
            const int u = 63 + d;
            wait1(f1, u);              // h1(u) ready + h1/tstage guards
            load_afrags(h1g + (long)(u & 1) * GS, lane, fb);
            vm_drain();
            floatx4 aR = {0,0,0,0}, aZ = aR, aNI = aR, aNH = aR;
            mm3_reg(fb, whR, whZ, whN, aR, aZ, aNH);   // off critical path
            wait1(f0, u + 1);          // fresh h0(u+1); also tstage guard
            load_afrags(h0g + (long)((u + 1) & 3) * GS, lane, fa);
            vm_drain();
            mm3_reg(fa, wiR, wiZ, wiN, aR, aZ, aNI);
            u16* tOut = temps + (long)d * (BB * SS);
            u16 hb[4], tb4[4];
#pragma unroll
            for (int r = 0; r < 4; ++r) {
                float rr = sigm(aR[r] + bir);
                float zz = sigm(aZ[r] + biz);
                float nn = tanh_f(aNI[r] + bin + rr * (aNH[r] + bhn));
                float hv = (1.f - zz) * nn + zz * hf[r];
                hf[r] = hv;
                u16 v = f2bf(hv);
                hb[r] = v;
#pragma unroll
                for (int i = 0; i < 15; ++i)
                    wreg[r][i] = (wreg[r][i] >> 16) | (wreg[r][i + 1] << 16);
                wreg[r][15] = (wreg[r][15] >> 16) | ((u32)v << 16);
                float tacc = btv;
#pragma unroll
                for (int i = 0; i < 16; ++i) {
                    u32 wv = wreg[r][i];
                    tacc += __uint_as_float(wv << 16) * wt[2 * i];
                    tacc += __uint_as_float(wv & 0xffff0000u) * wt[2 * i + 1];
                }
                u16 tb = f2bf(tacc);
                tb4[r] = tb;
                tOut[(long)(b0g + quad * 4 + r) * SS + sg] = tb;  // cached
            }
            staged_store(h1g + (long)((u + 1) & 1) * GS + wbase, ldsH, hb,
                         l15, quad, lane);
            staged_store(tsg + (long)(d & 1) * GS + wbase, ldsT, tb4,
                         l15, quad, lane);
            vm_drain();
            set_flag(f1 + myflag, u + 1);
        }
    }
}

// ---------------------------------------------------------------------------
// frames epilogue (parallel, MFMA): per batch b,
//   P[e][c] = temp(e)[b] . Ws[c];  frames[b][e][c] = x_last + cumsum(P + bs)
// Wave w computes e-tile w (16 e-rows) x 5 c-tiles via 16x16x32 MFMA.
// ---------------------------------------------------------------------------
__global__ __launch_bounds__(256) void frames_kernel(
    const u16* __restrict__ temps, const float* __restrict__ x,
    const u16* __restrict__ wsb, const float* __restrict__ bs,
    float* __restrict__ outp)
{
    const int b = blockIdx.x, tid = threadIdx.x;
    const int wave = tid >> 6, lane = tid & 63;
    const int l15 = lane & 15, quad = lane >> 4;
    __shared__ float P[64][81];

    const int e0 = wave * 16;
    floatx4 acc[5];
#pragma unroll
    for (int ct = 0; ct < 5; ++ct) acc[ct] = (floatx4){0.f, 0.f, 0.f, 0.f};
    const u16* aBase =
        temps + (long)(e0 + l15) * (BB * SS) + (long)b * SS + quad * 8;
#pragma unroll
    for (int kc = 0; kc < 16; ++kc) {
        short8 a = *(const short8*)(aBase + kc * 32);
#pragma unroll
        for (int ct = 0; ct < 5; ++ct) {
            const u16* wp = wsb + (long)(ct * 16 + l15) * SS + quad * 8 + kc * 32;
            MFMA_BF16(a, wp, acc[ct]);
        }
    }
#pragma unroll
    for (int ct = 0; ct < 5; ++ct)
#pragma unroll
        for (int r = 0; r < 4; ++r)
            P[e0 + quad * 4 + r][ct * 16 + l15] = acc[ct][r];
    __syncthreads();

    const int c = tid;
    if (c < CC) {
        float cum = x[((long)b * TT + (TT - 1)) * CC + c];
        const float bsv = bs[c];
        for (int e = 0; e < TT; ++e) {
            cum += P[e][c] + bsv;
            outp[(long)b * TT * CC + (long)e * CC + c] = cum;
        }
    }
}

// ---------------------------------------------------------------------------
extern "C" void kernel_launch(void* const* d_in, const int* in_sizes, int n_in,
                              void* d_out, int out_size, void* d_ws, size_t ws_size,
                              hipStream_t stream)
{
    const float* x    = (const float*)d_in[0];
    const float* Wih0 = (const float*)d_in[1];
    const float* Whh0 = (const float*)d_in[2];
    const float* bih0 = (const float*)d_in[3];
    const float* bhh0 = (const float*)d_in[4];
    const float* Wih1 = (const float*)d_in[5];
    const float* Whh1 = (const float*)d_in[6];
    const float* bih1 = (const float*)d_in[7];
    const float* bhh1 = (const float*)d_in[8];
    const float* Wt   = (const float*)d_in[9];
    const float* bt   = (const float*)d_in[10];
    const float* Ws   = (const float*)d_in[11];
    const float* bs   = (const float*)d_in[12];
    float* outp = (float*)d_out;

    char* p = (char*)d_ws;
    auto alloc = [&](size_t bytes) -> char* {
        char* r = p; p += (bytes + 255) & ~(size_t)255; return r;
    };
    u16* h0buf = (u16*)alloc((size_t)NGRP * 4 * GS * 2);
    u16* h1buf = (u16*)alloc((size_t)NGRP * 2 * GS * 2);
    u16* tstage = (u16*)alloc((size_t)NGRP * 2 * GS * 2);
    u16* xbf = (u16*)alloc((size_t)BB * TT * CPAD * 2);
    u16* wi0 = (u16*)alloc((size_t)NGATE * CPAD * 2);
    u16* wh0 = (u16*)alloc((size_t)NGATE * SS * 2);
    u16* wi1 = (u16*)alloc((size_t)NGATE * SS * 2);
    u16* wh1 = (u16*)alloc((size_t)NGATE * SS * 2);
    u16* Mbf = (u16*)alloc((size_t)NGATE * SS * 2);
    u16* wsb = (u16*)alloc((size_t)80 * SS * 2);
    float* c0vec = (float*)alloc((size_t)NGATE * 4);
    float* gi0i  = (float*)alloc((size_t)BB * NGATE * 4);
    u16* temps = (u16*)alloc((size_t)TT * BB * SS * 2);
    int* gflags = (int*)alloc((size_t)NGRP * 64 * 4);

    hipMemsetAsync(h0buf, 0, (size_t)NGRP * 4 * GS * 2, stream);
    hipMemsetAsync(h1buf, 0, (size_t)NGRP * 2 * GS * 2, stream);
    hipMemsetAsync(gflags, 0, (size_t)NGRP * 64 * 4, stream);

    prep1_kernel<<<1024, 256, 0, stream>>>(x, Wih0, Whh0, Wih1, Whh1, Ws,
                                           xbf, wi0, wh0, wi1, wh1, wsb);
    prep2_kernel<<<1024, 256, 0, stream>>>(x, Wih0, Ws, bs, Mbf, c0vec, gi0i);

    persist_kernel<<<NGRP * GBLK, 256, 0, stream>>>(
        xbf, wi0, wh0, wi1, wh1, Mbf, bih0, bhh0, bih1, bhh1,
        c0vec, gi0i, Wt, bt, h0buf, h1buf, tstage, temps, gflags);

    frames_kernel<<<BB, 256, 0, stream>>>(temps, x, wsb, bs, outp);
}

// Round 7
// 2423.130 us; speedup vs baseline: 1.1229x; 1.0234x over previous
//
#include <hip/hip_runtime.h>
#include <stdint.h>

typedef unsigned short u16;
typedef uint32_t u32;
typedef __attribute__((ext_vector_type(8))) short short8;
typedef __attribute__((ext_vector_type(4))) float floatx4;
typedef __attribute__((ext_vector_type(2))) unsigned int u32x2;

constexpr int BB = 128;     // batch
constexpr int TT = 64;      // time steps
constexpr int CC = 66;      // frame channels
constexpr int CPAD = 96;    // C padded to multiple of 32 (MFMA K-chunk)
constexpr int SS = 512;     // hidden
constexpr int NGATE = 1536; // 3*S
constexpr int NGRP = 8;     // independent batch groups (16 batches each)
constexpr int GBLK = 16;    // blocks per group (s-split by 32)
constexpr int GS = 16 * SS; // per-group state slab elements (16 x 512)

// State slabs (h0/h1/tstage): FRAGMENT-ORDER layout slab[(s>>3)][m][s&7]
// ([64][16][8] u16).  Consumer dwordx4 at slab + kc*512 + lane*8 reads a
// contiguous 1KB block.  Producer: wave stages 512B in LDS, emits 64
// coalesced dwordx2 (round 6; WRITE_SIZE regression fixed, confirmed).
//
// Sync (round 7): per-(group,layer,step) AGGREGATE COUNTERS.  Producer wave:
// one relaxed agent-scope fetch_add into cnt[step]; consumer: broadcast
// (wave-uniform) poll of ONE word until ==32.  Replaces the 32-flag
// gather-poll storm that was queueing at the MALL ahead of the critical
// flag-store/state-load operations.  Guard mapping: cnt[s]==32 <=> old
// f[]>=s for all 32 producer waves; s<=0 means initially-satisfied.

__device__ __forceinline__ u16 f2bf(float f) {
    u32 u = __float_as_uint(f);
    u32 r = (u + 0x7fffu + ((u >> 16) & 1u)) >> 16;
    return (u16)r;
}
__device__ __forceinline__ float bf2f(u16 h) {
    return __uint_as_float(((u32)h) << 16);
}
__device__ __forceinline__ float sigm(float x) { return 1.f / (1.f + __expf(-x)); }
__device__ __forceinline__ float tanh_f(float x) { return 1.f - 2.f / (1.f + __expf(2.f * x)); }

// ---- coherence-bypass primitives (MALL-coherent, no cache maintenance) ----
__device__ __forceinline__ void load_issue_cc(const u16* p, short8& d) {
    asm volatile("global_load_dwordx4 %0, %1, off sc0 sc1"
                 : "=v"(d) : "v"(p));
}
__device__ __forceinline__ void store_u64_cc(u16* p, u32x2 v) {
    asm volatile("global_store_dwordx2 %0, %1, off sc0 sc1"
                 :: "v"(p), "v"(v) : "memory");
}
__device__ __forceinline__ void vm_drain() {
    asm volatile("s_waitcnt vmcnt(0)" ::: "memory");
}

// ---------------------------------------------------------------------------
// prep1: bf16 conversion of x (padded to 96), the 4 GRU weight matrices,
// and Ws -> bf16 [80][512] (c-padded) for the MFMA frames epilogue.
// ---------------------------------------------------------------------------
__global__ void prep1_kernel(const float* __restrict__ x,
                             const float* __restrict__ Wih0,
                             const float* __restrict__ Whh0,
                             const float* __restrict__ Wih1,
                             const float* __restrict__ Whh1,
                             const float* __restrict__ Ws,
                             u16* __restrict__ xbf, u16* __restrict__ wi0,
                             u16* __restrict__ wh0, u16* __restrict__ wi1,
                             u16* __restrict__ wh1, u16* __restrict__ wsb)
{
    const int N_xbf = BB * TT * CPAD;
    const int N_wi0 = NGATE * CPAD;
    const int N_whh = NGATE * SS;
    const int N_wsb = 80 * SS;
    const long total = (long)N_xbf + N_wi0 + 3L * N_whh + N_wsb;
    for (long i = (long)blockIdx.x * blockDim.x + threadIdx.x; i < total;
         i += (long)gridDim.x * blockDim.x) {
        long idx = i;
        if (idx < N_xbf) {
            int c = idx % CPAD; int bt = idx / CPAD;
            float v = (c < CC) ? x[(long)bt * CC + c] : 0.f;
            xbf[idx] = f2bf(v); continue;
        }
        idx -= N_xbf;
        if (idx < N_wi0) {
            int c = idx % CPAD; int n = idx / CPAD;
            float v = (c < CC) ? Wih0[(long)n * CC + c] : 0.f;
            wi0[idx] = f2bf(v); continue;
        }
        idx -= N_wi0;
        if (idx < N_whh) { wh0[idx] = f2bf(Whh0[idx]); continue; }
        idx -= N_whh;
        if (idx < N_whh) { wi1[idx] = f2bf(Wih1[idx]); continue; }
        idx -= N_whh;
        if (idx < N_whh) { wh1[idx] = f2bf(Whh1[idx]); continue; }
        idx -= N_whh;
        {
            int s = idx % SS; int c = idx / SS;
            wsb[idx] = (c < CC) ? f2bf(Ws[(long)c * SS + s]) : (u16)0;
        }
    }
}

// ---------------------------------------------------------------------------
// prep2: M = Wih0[:, :66] @ Ws (bf16); c0vec = Wih0 @ bs; gi0i = x_last@Wih0^T
// ---------------------------------------------------------------------------
__global__ void prep2_kernel(const float* __restrict__ x,
                             const float* __restrict__ Wih0,
                             const float* __restrict__ Ws,
                             const float* __restrict__ bs,
                             u16* __restrict__ Mbf, float* __restrict__ c0vec,
                             float* __restrict__ gi0i)
{
    const long NM = (long)NGATE * SS;
    const long NC = NGATE;
    const long NG = (long)BB * NGATE;
    const long total = NM + NC + NG;
    for (long i = (long)blockIdx.x * blockDim.x + threadIdx.x; i < total;
         i += (long)gridDim.x * blockDim.x) {
        long idx = i;
        if (idx < NM) {
            int s = idx % SS; int g = idx / SS;
            float acc = 0.f;
            for (int c = 0; c < CC; ++c)
                acc += Wih0[(long)g * CC + c] * Ws[(long)c * SS + s];
            Mbf[idx] = f2bf(acc); continue;
        }
        idx -= NM;
        if (idx < NC) {
            int g = idx;
            float acc = 0.f;
            for (int c = 0; c < CC; ++c) acc += Wih0[(long)g * CC + c] * bs[c];
            c0vec[g] = acc; continue;
        }
        idx -= NC;
        {
            int g = idx % NGATE; int b = idx / NGATE;
            float acc = 0.f;
            const float* xl = x + ((long)b * TT + (TT - 1)) * CC;
            for (int c = 0; c < CC; ++c) acc += xl[c] * Wih0[(long)g * CC + c];
            gi0i[idx] = acc;
        }
    }
}

// ---------------------------------------------------------------------------
// A-fragment load from a fragment-order slab: 16 coherent dwordx4, each a
// CONTIGUOUS 1KB block.  lane(l15,quad) gets A[m=l15][k=kc*32+quad*8+j].
// ---------------------------------------------------------------------------
__device__ __forceinline__ void load_afrags(const u16* __restrict__ st,
                                            int lane, short8* a) {
#pragma unroll
    for (int kc = 0; kc < 16; ++kc)
        load_issue_cc(st + (long)kc * 512 + lane * 8, a[kc]);
}

#define MFMA_BF16(a, wp, acc) \
    acc = __builtin_amdgcn_mfma_f32_16x16x32_bf16(a, *(const short8*)(wp), acc, 0, 0, 0)

// Triple-gate MFMA over K=512 with register-resident A fragments.
__device__ __forceinline__ void mm3_reg(const short8* a,
                                        const u16* __restrict__ w0,
                                        const u16* __restrict__ w1,
                                        const u16* __restrict__ w2,
                                        floatx4& A0, floatx4& A1, floatx4& A2) {
#pragma unroll
    for (int kc = 0; kc < 16; ++kc) {
        const int k = kc << 5;
        MFMA_BF16(a[kc], w0 + k, A0);
        MFMA_BF16(a[kc], w1 + k, A1);
        MFMA_BF16(a[kc], w2 + k, A2);
    }
}

// Triple-gate MFMA, A direct from read-only cached global (x input, K=96).
template <int K>
__device__ __forceinline__ void mm3_g(const u16* __restrict__ aP,
                                      const u16* __restrict__ w0,
                                      const u16* __restrict__ w1,
                                      const u16* __restrict__ w2,
                                      floatx4& A0, floatx4& A1, floatx4& A2) {
#pragma unroll
    for (int k = 0; k < K; k += 32) {
        short8 a = *(const short8*)(aP + k);
        MFMA_BF16(a, w0 + k, A0);
        MFMA_BF16(a, w1 + k, A1);
        MFMA_BF16(a, w2 + k, A2);
    }
}

// ---------------------------------------------------------------------------
// Counter-based sync (relaxed agent-scope, MALL-coherent).
// waitc2: lanes<32 poll c0[s0], lanes>=32 poll c1[s1]; s<=0 => satisfied.
// waitc1: all lanes broadcast-poll c[s] (caller guarantees s>0).
// bump:   one fetch_add per producer wave.
// ---------------------------------------------------------------------------
__device__ __forceinline__ void waitc2(const int* __restrict__ c0, int s0,
                                       const int* __restrict__ c1, int s1) {
    const int lane = threadIdx.x & 63;
    const int* p = (lane < 32) ? (c0 + s0) : (c1 + s1);
    const bool act = ((lane < 32) ? s0 : s1) > 0;
    for (;;) {
        int v = 32;
        if (act)
            v = __hip_atomic_load(p, __ATOMIC_RELAXED, __HIP_MEMORY_SCOPE_AGENT);
        if (__all(v >= 32)) break;
        __builtin_amdgcn_s_sleep(2);
    }
    asm volatile("" ::: "memory");
}

__device__ __forceinline__ void waitc1(const int* __restrict__ c, int s) {
    const int* p = c + s;
    for (;;) {
        int v = __hip_atomic_load(p, __ATOMIC_RELAXED, __HIP_MEMORY_SCOPE_AGENT);
        if (__all(v >= 32)) break;
        __builtin_amdgcn_s_sleep(2);
    }
    asm volatile("" ::: "memory");
}

__device__ __forceinline__ void bump(int* c, int s) {
    if ((threadIdx.x & 63) == 0)
        __hip_atomic_fetch_add(c + s, 1, __ATOMIC_RELAXED,
                               __HIP_MEMORY_SCOPE_AGENT);
}

// ---------------------------------------------------------------------------
// staged_store: wave-local LDS transpose -> 64 coalesced dwordx2 stores.
// ---------------------------------------------------------------------------
__device__ __forceinline__ void staged_store(u16* __restrict__ gdst,  // slab+wbase
                                             u16* __restrict__ lds,   // 256 elems
                                             const u16 hb[4],
                                             int l15, int quad, int lane)
{
#pragma unroll
    for (int r = 0; r < 4; ++r)
        lds[((l15 >> 3) << 7) + ((quad << 2) + r) * 8 + (l15 & 7)] = hb[r];
    __builtin_amdgcn_wave_barrier();
    const u32* lp = (const u32*)(lds + (lane << 2));
    u32x2 v; v[0] = lp[0]; v[1] = lp[1];
    store_u64_cc(gdst + (lane << 2), v);
    __builtin_amdgcn_wave_barrier();
}

// ---------------------------------------------------------------------------
// Persistent kernel, wave-decoupled dataflow.  Group g = blockIdx>>4 owns
// batches [16g,16g+16); block rank = blockIdx&15 owns s-slice 32*rank..+32.
// Waves 0,1 = layer-0 (s-sub 0/1), waves 2,3 = layer-1.  Per-wave counter
// gating; no __syncthreads.  h0 depth 4, h1/tstage depth 2.
// ---------------------------------------------------------------------------
__global__ __launch_bounds__(256, 1) void persist_kernel(
    const u16* __restrict__ xbf,
    const u16* __restrict__ wi0, const u16* __restrict__ wh0,
    const u16* __restrict__ wi1, const u16* __restrict__ wh1,
    const u16* __restrict__ Mbf,
    const float* __restrict__ bih0, const float* __restrict__ bhh0,
    const float* __restrict__ bih1, const float* __restrict__ bhh1,
    const float* __restrict__ c0vec, const float* __restrict__ gi0i,
    const float* __restrict__ Wt, const float* __restrict__ bt,
    u16* __restrict__ h0buf,   // [NGRP][4][slab 8192]
    u16* __restrict__ h1buf,   // [NGRP][2][slab 8192]
    u16* __restrict__ tstage,  // [NGRP][2][slab 8192]
    u16* __restrict__ temps,   // [64][128][512] (cached; read by frames)
    int* __restrict__ gcnt)    // [NGRP][2][128] counters
{
    const int tid = threadIdx.x;
    const int wave = tid >> 6, lane = tid & 63;
    const int l15 = lane & 15, quad = lane >> 4;
    const int grp = blockIdx.x >> 4, rank = blockIdx.x & 15;
    const int b0g = grp * 16;
    const int wsub = wave & 1;
    const int sg = rank * 32 + wsub * 16 + l15;
    const bool l0w = wave < 2;

    __shared__ u16 stg[4][512];           // per-wave: [0..255] h, [256..511] t
    u16* const ldsH = &stg[wave][0];
    u16* const ldsT = &stg[wave][256];

    // wave's slab element base: (S0>>3)*128, S0 = rank*32 + wsub*16
    const int wbase = (rank * 4 + wsub * 2) << 7;

    u16* const h0g = h0buf + (long)grp * 4 * GS;
    u16* const h1g = h1buf + (long)grp * 2 * GS;
    u16* const tsg = tstage + (long)grp * 2 * GS;
    int* const c0 = gcnt + grp * 256;
    int* const c1 = c0 + 128;

    // ---- per-thread constants & register state ----
    float bir, biz, bin, bhn;
    float c0r = 0.f, c0z = 0.f, c0n = 0.f;
    float hf[4] = {0.f, 0.f, 0.f, 0.f};
    float gi[12];
    float wt[32]; float btv = 0.f;
    u32 wreg[4][16];
#pragma unroll
    for (int r = 0; r < 4; ++r)
#pragma unroll
        for (int i = 0; i < 16; ++i) wreg[r][i] = 0u;

    if (l0w) {
        bir = bih0[sg] + bhh0[sg];
        biz = bih0[512 + sg] + bhh0[512 + sg];
        bin = bih0[1024 + sg];
        bhn = bhh0[1024 + sg];
        c0r = c0vec[sg]; c0z = c0vec[512 + sg]; c0n = c0vec[1024 + sg];
#pragma unroll
        for (int g3 = 0; g3 < 3; ++g3)
#pragma unroll
            for (int r = 0; r < 4; ++r)
                gi[g3 * 4 + r] =
                    gi0i[(long)(b0g + quad * 4 + r) * NGATE + g3 * 512 + sg];
    } else {
        bir = bih1[sg] + bhh1[sg];
        biz = bih1[512 + sg] + bhh1[512 + sg];
        bin = bih1[1024 + sg];
        bhn = bhh1[1024 + sg];
#pragma unroll
        for (int j = 0; j < 32; ++j) wt[j] = Wt[j];
        btv = bt[0];
    }

    const u16 *wiR, *wiZ, *wiN, *whR, *whZ, *whN, *mR, *mZ, *mN;
    if (l0w) {
        wiR = wi0 + (long)sg * CPAD + quad * 8;
        wiZ = wi0 + (long)(512 + sg) * CPAD + quad * 8;
        wiN = wi0 + (long)(1024 + sg) * CPAD + quad * 8;
        whR = wh0 + (long)sg * SS + quad * 8;
        whZ = wh0 + (long)(512 + sg) * SS + quad * 8;
        whN = wh0 + (long)(1024 + sg) * SS + quad * 8;
        mR = Mbf + (long)sg * SS + quad * 8;
        mZ = Mbf + (long)(512 + sg) * SS + quad * 8;
        mN = Mbf + (long)(1024 + sg) * SS + quad * 8;
    } else {
        wiR = wi1 + (long)sg * SS + quad * 8;
        wiZ = wi1 + (long)(512 + sg) * SS + quad * 8;
        wiN = wi1 + (long)(1024 + sg) * SS + quad * 8;
        whR = wh1 + (long)sg * SS + quad * 8;
        whZ = wh1 + (long)(512 + sg) * SS + quad * 8;
        whN = wh1 + (long)(1024 + sg) * SS + quad * 8;
        mR = mZ = mN = nullptr;
    }

    short8 fa[16], fb[16];

    if (l0w) {
        // ================= layer-0 wave: 127 steps =================
        // encoder t = 0..62: consume h0(t), x[t]; produce h0(t+1)
        for (int t = 0; t < 63; ++t) {
            waitc2(c0, t, c1, t - 3);  // data ready + depth-4 overwrite guard
            load_afrags(h0g + (long)(t & 3) * GS, lane, fa);
            floatx4 aR = {0,0,0,0}, aZ = aR, aNI = aR, aNH = aR;
            const u16* aP = xbf + ((long)(b0g + l15) * TT + t) * CPAD + quad * 8;
            mm3_g<CPAD>(aP, wiR, wiZ, wiN, aR, aZ, aNI);
            vm_drain();
            mm3_reg(fa, whR, whZ, whN, aR, aZ, aNH);
            u16 hb[4];
#pragma unroll
            for (int r = 0; r < 4; ++r) {
                float rr = sigm(aR[r] + bir);
                float zz = sigm(aZ[r] + biz);
                float nn = tanh_f(aNI[r] + bin + rr * (aNH[r] + bhn));
                float hv = (1.f - zz) * nn + zz * hf[r];
                hf[r] = hv;
                hb[r] = f2bf(hv);
            }
            staged_store(h0g + (long)((t + 1) & 3) * GS + wbase, ldsH, hb,
                         l15, quad, lane);
            vm_drain();
            bump(c0, t + 1);
        }
        // decoder d = 0..63: step index t = 63+d; produce h0 state 64+d
        for (int d = 0; d < 64; ++d) {
            const int t = 63 + d;
            waitc2(c0, t, c1, t - 3);  // h0 ready + depth-4 overwrite guard
            load_afrags(h0g + (long)(t & 3) * GS, lane, fa);
            vm_drain();
            floatx4 hR = {0,0,0,0}, hZ = hR, hN4 = hR;
            mm3_reg(fa, whR, whZ, whN, hR, hZ, hN4);   // off critical path
            if (d > 0) {   // gi(d) = gi(d-1) + M @ temp(d-1) + c0
                waitc1(c1, t);                           // temp(d-1) ready
                load_afrags(tsg + (long)((d - 1) & 1) * GS, lane, fb);
                vm_drain();
                floatx4 tR = {0,0,0,0}, tZ = tR, tN = tR;
                mm3_reg(fb, mR, mZ, mN, tR, tZ, tN);
#pragma unroll
                for (int r = 0; r < 4; ++r) {
                    gi[r] += tR[r] + c0r;
                    gi[4 + r] += tZ[r] + c0z;
                    gi[8 + r] += tN[r] + c0n;
                }
            }
            u16 hb[4];
#pragma unroll
            for (int r = 0; r < 4; ++r) {
                float rr = sigm(gi[r] + hR[r] + bir);
                float zz = sigm(gi[4 + r] + hZ[r] + biz);
                float nn = tanh_f(gi[8 + r] + bin + rr * (hN4[r] + bhn));
                float hv = (1.f - zz) * nn + zz * hf[r];
                hf[r] = hv;
                hb[r] = f2bf(hv);
            }
            staged_store(h0g + (long)((t + 1) & 3) * GS + wbase, ldsH, hb,
                         l15, quad, lane);
            vm_drain();
            bump(c0, t + 1);
        }
    } else {
        // ================= layer-1 wave: 127 steps =================
        // encoder u = 0..62: consume h0(u+1), h1(u); produce h1(u+1) + window
        for (int u = 0; u < 63; ++u) {
            if (u > 0) {
                waitc1(c1, u);         // h1(u) ready (also h1 overwrite guard)
            }
            load_afrags(h1g + (long)(u & 1) * GS, lane, fb);
            vm_drain();
            floatx4 aR = {0,0,0,0}, aZ = aR, aNI = aR, aNH = aR;
            mm3_reg(fb, whR, whZ, whN, aR, aZ, aNH);   // off critical path
            waitc1(c0, u + 1);         // fresh h0(u+1)
            load_afrags(h0g + (long)((u + 1) & 3) * GS, lane, fa);
            vm_drain();
            mm3_reg(fa, wiR, wiZ, wiN, aR, aZ, aNI);
            u16 hb[4];
#pragma unroll
            for (int r = 0; r < 4; ++r) {
                float rr = sigm(aR[r] + bir);
                float zz = sigm(aZ[r] + biz);
                float nn = tanh_f(aNI[r] + bin + rr * (aNH[r] + bhn));
                float hv = (1.f - zz) * nn + zz * hf[r];
                hf[r] = hv;
                u16 v = f2bf(hv);
                hb[r] = v;
#pragma unroll
                for (int i = 0; i < 15; ++i)
                    wreg[r][i] = (wreg[r][i] >> 16) | (wreg[r][i + 1] << 16);
                wreg[r][15] = (wreg[r][15] >> 16) | ((u32)v << 16);
            }
            staged_store(h1g + (long)((u + 1) & 1) * GS + wbase, ldsH, hb,
                         l15, quad, lane);
            vm_drain();
            bump(c1, u + 1);
        }
        // decoder d = 0..63: step u = 63+d; produce h1(64+d), temp(d)
        for (int d = 0; d < 64; ++d) {
            const int u = 63 + d;
            waitc1(c1, u);             // h1(u) ready + h1/tstage guards
            load_afrags(h1g + (long)(u & 1) * GS, lane, fb);
            vm_drain();
            floatx4 aR = {0,0,0,0}, aZ = aR, aNI = aR, aNH = aR;
            mm3_reg(fb, whR, whZ, whN, aR, aZ, aNH);   // off critical path
            waitc1(c0, u + 1);         // fresh h0(u+1); also tstage guard
            load_afrags(h0g + (long)((u + 1) & 3) * GS, lane, fa);
            vm_drain();
            mm3_reg(fa, wiR, wiZ, wiN, aR, aZ, aNI);
            u16* tOut = temps + (long)d * (BB * SS);
            u16 hb[4], tb4[4];
#pragma unroll
            for (int r = 0; r < 4; ++r) {
                float rr = sigm(aR[r] + bir);
                float zz = sigm(aZ[r] + biz);
                float nn = tanh_f(aNI[r] + bin + rr * (aNH[r] + bhn));
                float hv = (1.f - zz) * nn + zz * hf[r];
                hf[r] = hv;
                u16 v = f2bf(hv);
                hb[r] = v;
#pragma unroll
                for (int i = 0; i < 15; ++i)
                    wreg[r][i] = (wreg[r][i] >> 16) | (wreg[r][i + 1] << 16);
                wreg[r][15] = (wreg[r][15] >> 16) | ((u32)v << 16);
                float tacc = btv;
#pragma unroll
                for (int i = 0; i < 16; ++i) {
                    u32 wv = wreg[r][i];
                    tacc += __uint_as_float(wv << 16) * wt[2 * i];
                    tacc += __uint_as_float(wv & 0xffff0000u) * wt[2 * i + 1];
                }
                u16 tb = f2bf(tacc);
                tb4[r] = tb;
                tOut[(long)(b0g + quad * 4 + r) * SS + sg] = tb;  // cached
            }
            staged_store(h1g + (long)((u + 1) & 1) * GS + wbase, ldsH, hb,
                         l15, quad, lane);
            staged_store(tsg + (long)(d & 1) * GS + wbase, ldsT, tb4,
                         l15, quad, lane);
            vm_drain();
            bump(c1, u + 1);
        }
    }
}

// ---------------------------------------------------------------------------
// frames epilogue (parallel, MFMA): per batch b,
//   P[e][c] = temp(e)[b] . Ws[c];  frames[b][e][c] = x_last + cumsum(P + bs)
// Wave w computes e-tile w (16 e-rows) x 5 c-tiles via 16x16x32 MFMA.
// ---------------------------------------------------------------------------
__global__ __launch_bounds__(256) void frames_kernel(
    const u16* __restrict__ temps, const float* __restrict__ x,
    const u16* __restrict__ wsb, const float* __restrict__ bs,
    float* __restrict__ outp)
{
    const int b = blockIdx.x, tid = threadIdx.x;
    const int wave = tid >> 6, lane = tid & 63;
    const int l15 = lane & 15, quad = lane >> 4;
    __shared__ float P[64][81];

    const int e0 = wave * 16;
    floatx4 acc[5];
#pragma unroll
    for (int ct = 0; ct < 5; ++ct) acc[ct] = (floatx4){0.f, 0.f, 0.f, 0.f};
    const u16* aBase =
        temps + (long)(e0 + l15) * (BB * SS) + (long)b * SS + quad * 8;
#pragma unroll
    for (int kc = 0; kc < 16; ++kc) {
        short8 a = *(const short8*)(aBase + kc * 32);
#pragma unroll
        for (int ct = 0; ct < 5; ++ct) {
            const u16* wp = wsb + (long)(ct * 16 + l15) * SS + quad * 8 + kc * 32;
            MFMA_BF16(a, wp, acc[ct]);
        }
    }
#pragma unroll
    for (int ct = 0; ct < 5; ++ct)
#pragma unroll
        for (int r = 0; r < 4; ++r)
            P[e0 + quad * 4 + r][ct * 16 + l15] = acc[ct][r];
    __syncthreads();

    const int c = tid;
    if (c < CC) {
        float cum = x[((long)b * TT + (TT - 1)) * CC + c];
        const float bsv = bs[c];
        for (int e = 0; e < TT; ++e) {
            cum += P[e][c] + bsv;
            outp[(long)b * TT * CC + (long)e * CC + c] = cum;
        }
    }
}

// ---------------------------------------------------------------------------
extern "C" void kernel_launch(void* const* d_in, const int* in_sizes, int n_in,
                              void* d_out, int out_size, void* d_ws, size_t ws_size,
                              hipStream_t stream)
{
    const float* x    = (const float*)d_in[0];
    const float* Wih0 = (const float*)d_in[1];
    const float* Whh0 = (const float*)d_in[2];
    const float* bih0 = (const float*)d_in[3];
    const float* bhh0 = (const float*)d_in[4];
    const float* Wih1 = (const float*)d_in[5];
    const float* Whh1 = (const float*)d_in[6];
    const float* bih1 = (const float*)d_in[7];
    const float* bhh1 = (const float*)d_in[8];
    const float* Wt   = (const float*)d_in[9];
    const float* bt   = (const float*)d_in[10];
    const float* Ws   = (const float*)d_in[11];
    const float* bs   = (const float*)d_in[12];
    float* outp = (float*)d_out;

    char* p = (char*)d_ws;
    auto alloc = [&](size_t bytes) -> char* {
        char* r = p; p += (bytes + 255) & ~(size_t)255; return r;
    };
    u16* h0buf = (u16*)alloc((size_t)NGRP * 4 * GS * 2);
    u16* h1buf = (u16*)alloc((size_t)NGRP * 2 * GS * 2);
    u16* tstage = (u16*)alloc((size_t)NGRP * 2 * GS * 2);
    u16* xbf = (u16*)alloc((size_t)BB * TT * CPAD * 2);
    u16* wi0 = (u16*)alloc((size_t)NGATE * CPAD * 2);
    u16* wh0 = (u16*)alloc((size_t)NGATE * SS * 2);
    u16* wi1 = (u16*)alloc((size_t)NGATE * SS * 2);
    u16* wh1 = (u16*)alloc((size_t)NGATE * SS * 2);
    u16* Mbf = (u16*)alloc((size_t)NGATE * SS * 2);
    u16* wsb = (u16*)alloc((size_t)80 * SS * 2);
    float* c0vec = (float*)alloc((size_t)NGATE * 4);
    float* gi0i  = (float*)alloc((size_t)BB * NGATE * 4);
    u16* temps = (u16*)alloc((size_t)TT * BB * SS * 2);
    int* gcnt = (int*)alloc((size_t)NGRP * 256 * 4);

    hipMemsetAsync(h0buf, 0, (size_t)NGRP * 4 * GS * 2, stream);
    hipMemsetAsync(h1buf, 0, (size_t)NGRP * 2 * GS * 2, stream);
    hipMemsetAsync(gcnt, 0, (size_t)NGRP * 256 * 4, stream);

    prep1_kernel<<<1024, 256, 0, stream>>>(x, Wih0, Whh0, Wih1, Whh1, Ws,
                                           xbf, wi0, wh0, wi1, wh1, wsb);
    prep2_kernel<<<1024, 256, 0, stream>>>(x, Wih0, Ws, bs, Mbf, c0vec, gi0i);

    persist_kernel<<<NGRP * GBLK, 256, 0, stream>>>(
        xbf, wi0, wh0, wi1, wh1, Mbf, bih0, bhh0, bih1, bhh1,
        c0vec, gi0i, Wt, bt, h0buf, h1buf, tstage, temps, gcnt);

    frames_kernel<<<BB, 256, 0, stream>>>(temps, x, wsb, bs, outp);
}